// Round 1
// baseline (588.572 us; speedup 1.0000x reference)
//
#include <hip/hip_runtime.h>
#include <math.h>

#define N_NODES 100000
#define N_EDGES 1600000
#define F_IN 8
#define HID 32
#define HEADS 4
#define F1 128    // HEADS*HID
#define F2 16     // OUT
#define SCAN_CHUNK 1024

__device__ __forceinline__ float leaky(float x){ return x > 0.f ? x : 0.2f * x; }
__device__ __forceinline__ float elu1(float x){ return x > 0.f ? x : __expf(x) - 1.f; }

// ---------------- CSR build ----------------
__global__ void k_count(const int* __restrict__ dst, int* __restrict__ deg){
    int e = blockIdx.x * 256 + threadIdx.x;
    if (e < N_EDGES) atomicAdd(&deg[dst[e]], 1);
}

__global__ void k_chunk_sums(const int* __restrict__ deg, int* __restrict__ chunkOff){
    __shared__ int sm[256];
    int t = threadIdx.x;
    int base = blockIdx.x * SCAN_CHUNK + t * 4;
    int s = 0;
    #pragma unroll
    for (int j = 0; j < 4; j++){ int g = base + j; if (g < N_NODES) s += deg[g]; }
    sm[t] = s; __syncthreads();
    for (int off = 128; off > 0; off >>= 1){
        if (t < off) sm[t] += sm[t + off];
        __syncthreads();
    }
    if (t == 0) chunkOff[blockIdx.x] = sm[0];
}

__global__ void k_scan_offsets(int* __restrict__ chunkOff, int nchunks){
    __shared__ int sm[128];
    int t = threadIdx.x;
    int v = (t < nchunks) ? chunkOff[t] : 0;
    sm[t] = v; __syncthreads();
    for (int off = 1; off < 128; off <<= 1){
        int x = (t >= off) ? sm[t - off] : 0;
        __syncthreads();
        sm[t] += x;
        __syncthreads();
    }
    int inc = sm[t];
    if (t < nchunks) chunkOff[t] = inc - v;   // exclusive scan
}

__global__ void k_scan_final(const int* __restrict__ deg, const int* __restrict__ chunkOff,
                             int* __restrict__ row_ptr, int* __restrict__ cursor){
    __shared__ int sm[256];
    int t = threadIdx.x;
    int base = blockIdx.x * SCAN_CHUNK + t * 4;
    int v[4]; int s = 0;
    #pragma unroll
    for (int j = 0; j < 4; j++){ int g = base + j; v[j] = (g < N_NODES) ? deg[g] : 0; s += v[j]; }
    sm[t] = s; __syncthreads();
    for (int off = 1; off < 256; off <<= 1){
        int x = (t >= off) ? sm[t - off] : 0;
        __syncthreads();
        sm[t] += x;
        __syncthreads();
    }
    int inc = sm[t];
    int run = inc - s + chunkOff[blockIdx.x];   // exclusive offset for this thread
    #pragma unroll
    for (int j = 0; j < 4; j++){
        int g = base + j;
        if (g < N_NODES){ cursor[g] = run; run += v[j]; row_ptr[g + 1] = run; }
    }
    if (blockIdx.x == 0 && t == 0) row_ptr[0] = 0;
}

__global__ void k_fill(const int* __restrict__ src, const int* __restrict__ dst,
                       int* __restrict__ cursor, int* __restrict__ esrc){
    int e = blockIdx.x * 256 + threadIdx.x;
    if (e < N_EDGES){
        int d = dst[e];
        int pos = atomicAdd(&cursor[d], 1);
        esrc[pos] = src[e];
    }
}

// ---------------- Layer 1 dense: h1 = x@W1 ; a_s1/a_d1 per head ----------------
__global__ __launch_bounds__(256) void k_dense1(
    const float* __restrict__ x, const float* __restrict__ W1,
    const float* __restrict__ as1w, const float* __restrict__ ad1w,
    float* __restrict__ h1, float* __restrict__ a_s1, float* __restrict__ a_d1){
    __shared__ float W1s[F_IN * F1];          // 1024
    __shared__ float atts[HEADS * HID];       // 128
    __shared__ float attd[HEADS * HID];       // 128
    __shared__ float xs[8 * F_IN];            // 64
    int t = threadIdx.x;
    ((float4*)W1s)[t] = ((const float4*)W1)[t];        // 256 * 4 = 1024 floats
    if (t < 128){ atts[t] = as1w[t]; attd[t] = ad1w[t]; }
    if (t < 64) xs[t] = x[blockIdx.x * 64 + t];
    __syncthreads();

    int ln = t >> 5, l32 = t & 31;
    int n = blockIdx.x * 8 + ln;               // N divisible by 8
    float xr[8];
    #pragma unroll
    for (int k = 0; k < 8; k++) xr[k] = xs[ln * 8 + k];
    int j0 = l32 * 4;
    float o0 = 0, o1 = 0, o2 = 0, o3 = 0;
    #pragma unroll
    for (int k = 0; k < 8; k++){
        float4 w4 = ((const float4*)(W1s + k * F1))[l32];
        o0 += xr[k] * w4.x; o1 += xr[k] * w4.y; o2 += xr[k] * w4.z; o3 += xr[k] * w4.w;
    }
    int hd = l32 >> 3;
    int dl = j0 & 31;
    float ps = o0 * atts[hd * 32 + dl] + o1 * atts[hd * 32 + dl + 1]
             + o2 * atts[hd * 32 + dl + 2] + o3 * atts[hd * 32 + dl + 3];
    float pd = o0 * attd[hd * 32 + dl] + o1 * attd[hd * 32 + dl + 1]
             + o2 * attd[hd * 32 + dl + 2] + o3 * attd[hd * 32 + dl + 3];
    ps += __shfl_down(ps, 4, 8); ps += __shfl_down(ps, 2, 8); ps += __shfl_down(ps, 1, 8);
    pd += __shfl_down(pd, 4, 8); pd += __shfl_down(pd, 2, 8); pd += __shfl_down(pd, 1, 8);
    if ((l32 & 7) == 0){ a_s1[n * 4 + hd] = ps; a_d1[n * 4 + hd] = pd; }
    float4 hv; hv.x = o0; hv.y = o1; hv.z = o2; hv.w = o3;
    *(float4*)(h1 + (size_t)n * F1 + j0) = hv;
}

// ---------------- Layer 1 aggregate: one wave per node ----------------
__global__ __launch_bounds__(256) void k_agg1(
    const float* __restrict__ h1, const float* __restrict__ a_s1, const float* __restrict__ a_d1,
    const int* __restrict__ row_ptr, const int* __restrict__ esrc,
    const float* __restrict__ b1, float* __restrict__ hL1){
    int t = threadIdx.x;
    int wv = t >> 6, lane = t & 63;
    int n = blockIdx.x * 4 + wv;               // N divisible by 4
    float4 ad4 = *(const float4*)(a_d1 + n * 4);
    float4 as4 = *(const float4*)(a_s1 + n * 4);
    // max phase (self-loop seeds every lane; max is idempotent)
    float m0 = leaky(as4.x + ad4.x), m1 = leaky(as4.y + ad4.y);
    float m2 = leaky(as4.z + ad4.z), m3 = leaky(as4.w + ad4.w);
    int start = row_ptr[n], end = row_ptr[n + 1];
    for (int i = start + lane; i < end; i += 64){
        int s = esrc[i];
        float4 as = *(const float4*)(a_s1 + s * 4);
        m0 = fmaxf(m0, leaky(as.x + ad4.x));
        m1 = fmaxf(m1, leaky(as.y + ad4.y));
        m2 = fmaxf(m2, leaky(as.z + ad4.z));
        m3 = fmaxf(m3, leaky(as.w + ad4.w));
    }
    #pragma unroll
    for (int off = 32; off >= 1; off >>= 1){
        m0 = fmaxf(m0, __shfl_xor(m0, off));
        m1 = fmaxf(m1, __shfl_xor(m1, off));
        m2 = fmaxf(m2, __shfl_xor(m2, off));
        m3 = fmaxf(m3, __shfl_xor(m3, off));
    }
    int hd = lane >> 4;                 // lane owns dims 2*lane, 2*lane+1; head = (2*lane)/32
    float adh = hd == 0 ? ad4.x : hd == 1 ? ad4.y : hd == 2 ? ad4.z : ad4.w;
    float ash = hd == 0 ? as4.x : hd == 1 ? as4.y : hd == 2 ? as4.z : as4.w;
    float mh  = hd == 0 ? m0   : hd == 1 ? m1   : hd == 2 ? m2   : m3;
    int d0 = 2 * lane;
    // self-loop contribution
    float w = __expf(leaky(ash + adh) - mh);
    float den = w;
    float2 hv = *(const float2*)(h1 + (size_t)n * F1 + d0);
    float acc0 = w * hv.x, acc1 = w * hv.y;
    // real edges (loop is wave-uniform)
    for (int i = start; i < end; i++){
        int s = esrc[i];
        float e = leaky(a_s1[s * 4 + hd] + adh);
        float ww = __expf(e - mh);
        den += ww;
        float2 hh = *(const float2*)(h1 + (size_t)s * F1 + d0);
        acc0 += ww * hh.x; acc1 += ww * hh.y;
    }
    float inv = 1.f / (den + 1e-16f);
    float2 ov;
    ov.x = elu1(acc0 * inv + b1[d0]);
    ov.y = elu1(acc1 * inv + b1[d0 + 1]);
    *(float2*)(hL1 + (size_t)n * F1 + d0) = ov;
}

// ---------------- Layer 2 dense: h2 = hL1@W2 ; a_s2/a_d2 ----------------
__global__ __launch_bounds__(256) void k_dense2(
    const float* __restrict__ hL1, const float* __restrict__ W2,
    const float* __restrict__ as2w, const float* __restrict__ ad2w,
    float* __restrict__ h2, float* __restrict__ a_s2, float* __restrict__ a_d2){
    __shared__ float W2s[F1 * F2];    // 2048
    __shared__ float hs[16 * F1];     // 2048
    int t = threadIdx.x;
    ((float4*)W2s)[t]       = ((const float4*)W2)[t];
    ((float4*)W2s)[t + 256] = ((const float4*)W2)[t + 256];
    const float4* hsrc = (const float4*)(hL1 + (size_t)blockIdx.x * 16 * F1);
    ((float4*)hs)[t]       = hsrc[t];
    ((float4*)hs)[t + 256] = hsrc[t + 256];
    __syncthreads();

    int ln = t >> 4, dim = t & 15;
    int n = blockIdx.x * 16 + ln;      // N divisible by 16
    float dot = 0.f;
    const float4* hrow = (const float4*)(hs + ln * F1);
    #pragma unroll 8
    for (int k4 = 0; k4 < 32; k4++){
        float4 hv = hrow[k4];
        int k = k4 * 4;
        dot += hv.x * W2s[(k    ) * 16 + dim];
        dot += hv.y * W2s[(k + 1) * 16 + dim];
        dot += hv.z * W2s[(k + 2) * 16 + dim];
        dot += hv.w * W2s[(k + 3) * 16 + dim];
    }
    float ps = dot * as2w[dim];
    float pd = dot * ad2w[dim];
    #pragma unroll
    for (int off = 8; off >= 1; off >>= 1){
        ps += __shfl_down(ps, off, 16);
        pd += __shfl_down(pd, off, 16);
    }
    if (dim == 0){ a_s2[n] = ps; a_d2[n] = pd; }
    h2[(size_t)n * 16 + dim] = dot;
}

// ---------------- Layer 2 aggregate + classifier ----------------
__global__ __launch_bounds__(256) void k_agg2(
    const float* __restrict__ h2, const float* __restrict__ a_s2, const float* __restrict__ a_d2,
    const int* __restrict__ row_ptr, const int* __restrict__ esrc,
    const float* __restrict__ b2, const float* __restrict__ Wc1, const float* __restrict__ bc1,
    const float* __restrict__ Wc2, const float* __restrict__ bc2, float* __restrict__ out){
    __shared__ float es[16 * 16];
    int t = threadIdx.x;
    int ln = t >> 4, sub = t & 15;
    int n = blockIdx.x * 16 + ln;      // N divisible by 16
    float adn = a_d2[n], asn = a_s2[n];
    float m = leaky(asn + adn);
    int start = row_ptr[n], end = row_ptr[n + 1];
    for (int i = start + sub; i < end; i += 16){
        m = fmaxf(m, leaky(a_s2[esrc[i]] + adn));
    }
    #pragma unroll
    for (int off = 8; off >= 1; off >>= 1) m = fmaxf(m, __shfl_xor(m, off, 16));

    float w = __expf(leaky(asn + adn) - m);
    float den = w;
    float acc = w * h2[(size_t)n * 16 + sub];
    for (int i = start; i < end; i++){
        int s = esrc[i];
        float ww = __expf(leaky(a_s2[s] + adn) - m);
        den += ww;
        acc += ww * h2[(size_t)s * 16 + sub];
    }
    float embv = elu1(acc / (den + 1e-16f) + b2[sub]);
    out[(size_t)n * 16 + sub] = embv;
    es[ln * 16 + sub] = embv;
    __syncthreads();
    float contrib = 0.f;
    if (sub < 8){
        float hid = bc1[sub];
        #pragma unroll
        for (int d = 0; d < 16; d++) hid += es[ln * 16 + d] * Wc1[d * 8 + sub];
        hid = fmaxf(hid, 0.f);
        contrib = hid * Wc2[sub];
    }
    #pragma unroll
    for (int off = 8; off >= 1; off >>= 1) contrib += __shfl_xor(contrib, off, 16);
    if (sub == 0) out[(size_t)N_NODES * 16 + n] = 1.f / (1.f + __expf(-(contrib + bc2[0])));
}

extern "C" void kernel_launch(void* const* d_in, const int* in_sizes, int n_in,
                              void* d_out, int out_size, void* d_ws, size_t ws_size,
                              hipStream_t stream){
    const float* x    = (const float*)d_in[0];
    const int*   ei   = (const int*)d_in[1];
    const float* W1   = (const float*)d_in[2];
    const float* as1w = (const float*)d_in[3];
    const float* ad1w = (const float*)d_in[4];
    const float* b1   = (const float*)d_in[5];
    const float* W2   = (const float*)d_in[6];
    const float* as2w = (const float*)d_in[7];
    const float* ad2w = (const float*)d_in[8];
    const float* b2   = (const float*)d_in[9];
    const float* Wc1  = (const float*)d_in[10];
    const float* bc1  = (const float*)d_in[11];
    const float* Wc2  = (const float*)d_in[12];
    const float* bc2  = (const float*)d_in[13];
    float* out = (float*)d_out;
    const int* src = ei;
    const int* dst = ei + N_EDGES;

    float* ws   = (float*)d_ws;
    float* h1   = ws;                                  // N*128
    float* hL1  = h1  + (size_t)N_NODES * F1;          // N*128
    float* a_s1 = hL1 + (size_t)N_NODES * F1;          // N*4
    float* a_d1 = a_s1 + (size_t)N_NODES * 4;          // N*4
    float* h2   = a_d1 + (size_t)N_NODES * 4;          // N*16
    float* a_s2 = h2   + (size_t)N_NODES * 16;         // N
    float* a_d2 = a_s2 + N_NODES;                      // N
    int* deg      = (int*)(a_d2 + N_NODES);            // N
    int* row_ptr  = deg + N_NODES;                     // N+1
    int* cursor   = row_ptr + N_NODES + 1;             // N
    int* chunkOff = cursor + N_NODES;                  // 128
    int* esrc     = chunkOff + 128;                    // E

    hipMemsetAsync(deg, 0, N_NODES * sizeof(int), stream);
    int nchunks = (N_NODES + SCAN_CHUNK - 1) / SCAN_CHUNK;   // 98
    k_count<<<N_EDGES / 256, 256, 0, stream>>>(dst, deg);
    k_chunk_sums<<<nchunks, 256, 0, stream>>>(deg, chunkOff);
    k_scan_offsets<<<1, 128, 0, stream>>>(chunkOff, nchunks);
    k_scan_final<<<nchunks, 256, 0, stream>>>(deg, chunkOff, row_ptr, cursor);
    k_fill<<<N_EDGES / 256, 256, 0, stream>>>(src, dst, cursor, esrc);

    k_dense1<<<N_NODES / 8, 256, 0, stream>>>(x, W1, as1w, ad1w, h1, a_s1, a_d1);
    k_agg1<<<N_NODES / 4, 256, 0, stream>>>(h1, a_s1, a_d1, row_ptr, esrc, b1, hL1);
    k_dense2<<<N_NODES / 16, 256, 0, stream>>>(hL1, W2, as2w, ad2w, h2, a_s2, a_d2);
    k_agg2<<<N_NODES / 16, 256, 0, stream>>>(h2, a_s2, a_d2, row_ptr, esrc, b2, Wc1, bc1, Wc2, bc2, out);
}

// Round 2
// 476.318 us; speedup vs baseline: 1.2357x; 1.2357x over previous
//
#include <hip/hip_runtime.h>
#include <hip/hip_fp16.h>
#include <math.h>

#define N_NODES 100000
#define N_EDGES 1600000
#define F_IN 8
#define HID 32
#define HEADS 4
#define F1 128    // HEADS*HID
#define F2 16     // OUT
#define SCAN_CHUNK 1024

__device__ __forceinline__ float leaky(float x){ return x > 0.f ? x : 0.2f * x; }
__device__ __forceinline__ float elu1(float x){ return x > 0.f ? x : __expf(x) - 1.f; }

// ---------------- CSR build ----------------
__global__ void k_count(const int* __restrict__ dst, int* __restrict__ deg){
    int e = blockIdx.x * 256 + threadIdx.x;
    if (e < N_EDGES) atomicAdd(&deg[dst[e]], 1);
}

__global__ void k_chunk_sums(const int* __restrict__ deg, int* __restrict__ chunkOff){
    __shared__ int sm[256];
    int t = threadIdx.x;
    int base = blockIdx.x * SCAN_CHUNK + t * 4;
    int s = 0;
    #pragma unroll
    for (int j = 0; j < 4; j++){ int g = base + j; if (g < N_NODES) s += deg[g]; }
    sm[t] = s; __syncthreads();
    for (int off = 128; off > 0; off >>= 1){
        if (t < off) sm[t] += sm[t + off];
        __syncthreads();
    }
    if (t == 0) chunkOff[blockIdx.x] = sm[0];
}

__global__ void k_scan_offsets(int* __restrict__ chunkOff, int nchunks){
    __shared__ int sm[128];
    int t = threadIdx.x;
    int v = (t < nchunks) ? chunkOff[t] : 0;
    sm[t] = v; __syncthreads();
    for (int off = 1; off < 128; off <<= 1){
        int x = (t >= off) ? sm[t - off] : 0;
        __syncthreads();
        sm[t] += x;
        __syncthreads();
    }
    int inc = sm[t];
    if (t < nchunks) chunkOff[t] = inc - v;   // exclusive scan
}

__global__ void k_scan_final(const int* __restrict__ deg, const int* __restrict__ chunkOff,
                             int* __restrict__ row_ptr, int* __restrict__ cursor){
    __shared__ int sm[256];
    int t = threadIdx.x;
    int base = blockIdx.x * SCAN_CHUNK + t * 4;
    int v[4]; int s = 0;
    #pragma unroll
    for (int j = 0; j < 4; j++){ int g = base + j; v[j] = (g < N_NODES) ? deg[g] : 0; s += v[j]; }
    sm[t] = s; __syncthreads();
    for (int off = 1; off < 256; off <<= 1){
        int x = (t >= off) ? sm[t - off] : 0;
        __syncthreads();
        sm[t] += x;
        __syncthreads();
    }
    int inc = sm[t];
    int run = inc - s + chunkOff[blockIdx.x];   // exclusive offset for this thread
    #pragma unroll
    for (int j = 0; j < 4; j++){
        int g = base + j;
        if (g < N_NODES){ cursor[g] = run; run += v[j]; row_ptr[g + 1] = run; }
    }
    if (blockIdx.x == 0 && t == 0) row_ptr[0] = 0;
}

__global__ void k_fill(const int* __restrict__ src, const int* __restrict__ dst,
                       int* __restrict__ cursor, int* __restrict__ esrc){
    int e = blockIdx.x * 256 + threadIdx.x;
    if (e < N_EDGES){
        int d = dst[e];
        int pos = atomicAdd(&cursor[d], 1);
        esrc[pos] = src[e];
    }
}

// ---------------- Layer 1 dense: h1 = x@W1 (fp16 out) ; a_s1/a_d1 per head ----------------
__global__ __launch_bounds__(256) void k_dense1(
    const float* __restrict__ x, const float* __restrict__ W1,
    const float* __restrict__ as1w, const float* __restrict__ ad1w,
    __half* __restrict__ h1h, float* __restrict__ a_s1, float* __restrict__ a_d1){
    __shared__ float W1s[F_IN * F1];          // 1024
    __shared__ float atts[HEADS * HID];       // 128
    __shared__ float attd[HEADS * HID];       // 128
    __shared__ float xs[8 * F_IN];            // 64
    int t = threadIdx.x;
    ((float4*)W1s)[t] = ((const float4*)W1)[t];        // 256 * 4 = 1024 floats
    if (t < 128){ atts[t] = as1w[t]; attd[t] = ad1w[t]; }
    if (t < 64) xs[t] = x[blockIdx.x * 64 + t];
    __syncthreads();

    int ln = t >> 5, l32 = t & 31;
    int n = blockIdx.x * 8 + ln;               // N divisible by 8
    float xr[8];
    #pragma unroll
    for (int k = 0; k < 8; k++) xr[k] = xs[ln * 8 + k];
    int j0 = l32 * 4;
    float o0 = 0, o1 = 0, o2 = 0, o3 = 0;
    #pragma unroll
    for (int k = 0; k < 8; k++){
        float4 w4 = ((const float4*)(W1s + k * F1))[l32];
        o0 += xr[k] * w4.x; o1 += xr[k] * w4.y; o2 += xr[k] * w4.z; o3 += xr[k] * w4.w;
    }
    int hd = l32 >> 3;
    int dl = j0 & 31;
    float ps = o0 * atts[hd * 32 + dl] + o1 * atts[hd * 32 + dl + 1]
             + o2 * atts[hd * 32 + dl + 2] + o3 * atts[hd * 32 + dl + 3];
    float pd = o0 * attd[hd * 32 + dl] + o1 * attd[hd * 32 + dl + 1]
             + o2 * attd[hd * 32 + dl + 2] + o3 * attd[hd * 32 + dl + 3];
    ps += __shfl_down(ps, 4, 8); ps += __shfl_down(ps, 2, 8); ps += __shfl_down(ps, 1, 8);
    pd += __shfl_down(pd, 4, 8); pd += __shfl_down(pd, 2, 8); pd += __shfl_down(pd, 1, 8);
    if ((l32 & 7) == 0){ a_s1[n * 4 + hd] = ps; a_d1[n * 4 + hd] = pd; }
    __half2* hp = (__half2*)(h1h + (size_t)n * F1 + j0);
    hp[0] = __floats2half2_rn(o0, o1);
    hp[1] = __floats2half2_rn(o2, o3);
}

// ---------------- Layer 1 aggregate: one wave per node, 2 edge-groups x 32 dim-lanes ----------------
__global__ __launch_bounds__(256) void k_agg1(
    const __half* __restrict__ h1h, const float* __restrict__ a_s1, const float* __restrict__ a_d1,
    const int* __restrict__ row_ptr, const int* __restrict__ esrc,
    const float* __restrict__ b1, float* __restrict__ hL1){
    int t = threadIdx.x;
    int wv = t >> 6, lane = t & 63;
    int n = blockIdx.x * 4 + wv;               // N divisible by 4
    int g = lane >> 5;                          // edge subgroup (0/1)
    int l = lane & 31;                          // dim-lane: owns dims 4l..4l+3
    int d0 = l * 4;
    int hd = l >> 3;                            // head for these dims

    float adh = a_d1[n * 4 + hd];
    float ash = a_s1[n * 4 + hd];

    float den = 0.f, acc0 = 0.f, acc1 = 0.f, acc2 = 0.f, acc3 = 0.f;
    if (g == 0){
        // self-loop (softmax shift m=0: logits are O(1), no overflow risk)
        float w = __expf(leaky(ash + adh));
        den = w;
        const __half2* hp = (const __half2*)(h1h + (size_t)n * F1 + d0);
        __half2 p01 = hp[0], p23 = hp[1];
        acc0 = w * __low2float(p01); acc1 = w * __high2float(p01);
        acc2 = w * __low2float(p23); acc3 = w * __high2float(p23);
    }
    int start = row_ptr[n], end = row_ptr[n + 1];
    int i = start + g;
    int lim = end - 2;                          // i and i+2 both valid while i < lim
    for (; i < lim; i += 4){
        int s0 = esrc[i], s1 = esrc[i + 2];
        float e0 = a_s1[s0 * 4 + hd];
        float e1 = a_s1[s1 * 4 + hd];
        const __half2* hp0 = (const __half2*)(h1h + (size_t)s0 * F1 + d0);
        const __half2* hp1 = (const __half2*)(h1h + (size_t)s1 * F1 + d0);
        __half2 a01 = hp0[0], a23 = hp0[1];
        __half2 b01 = hp1[0], b23 = hp1[1];
        float w0 = __expf(leaky(e0 + adh));
        float w1 = __expf(leaky(e1 + adh));
        den += w0 + w1;
        acc0 += w0 * __low2float(a01) + w1 * __low2float(b01);
        acc1 += w0 * __high2float(a01) + w1 * __high2float(b01);
        acc2 += w0 * __low2float(a23) + w1 * __low2float(b23);
        acc3 += w0 * __high2float(a23) + w1 * __high2float(b23);
    }
    if (i < end){
        int s0 = esrc[i];
        float w0 = __expf(leaky(a_s1[s0 * 4 + hd] + adh));
        const __half2* hp0 = (const __half2*)(h1h + (size_t)s0 * F1 + d0);
        __half2 a01 = hp0[0], a23 = hp0[1];
        den += w0;
        acc0 += w0 * __low2float(a01); acc1 += w0 * __high2float(a01);
        acc2 += w0 * __low2float(a23); acc3 += w0 * __high2float(a23);
    }
    // combine the two edge-groups (paired lanes share d0/hd)
    den  += __shfl_xor(den, 32);
    acc0 += __shfl_xor(acc0, 32);
    acc1 += __shfl_xor(acc1, 32);
    acc2 += __shfl_xor(acc2, 32);
    acc3 += __shfl_xor(acc3, 32);
    if (g == 0){
        float inv = 1.f / (den + 1e-16f);
        float4 b4 = *(const float4*)(b1 + d0);
        float4 ov;
        ov.x = elu1(acc0 * inv + b4.x);
        ov.y = elu1(acc1 * inv + b4.y);
        ov.z = elu1(acc2 * inv + b4.z);
        ov.w = elu1(acc3 * inv + b4.w);
        *(float4*)(hL1 + (size_t)n * F1 + d0) = ov;
    }
}

// ---------------- Layer 2 dense: h2 = hL1@W2 (fp16 out) ; a_s2/a_d2 ----------------
__global__ __launch_bounds__(256) void k_dense2(
    const float* __restrict__ hL1, const float* __restrict__ W2,
    const float* __restrict__ as2w, const float* __restrict__ ad2w,
    __half* __restrict__ h2h, float* __restrict__ a_s2, float* __restrict__ a_d2){
    __shared__ float W2s[F1 * F2];    // 2048
    __shared__ float hs[16 * F1];     // 2048
    int t = threadIdx.x;
    ((float4*)W2s)[t]       = ((const float4*)W2)[t];
    ((float4*)W2s)[t + 256] = ((const float4*)W2)[t + 256];
    const float4* hsrc = (const float4*)(hL1 + (size_t)blockIdx.x * 16 * F1);
    ((float4*)hs)[t]       = hsrc[t];
    ((float4*)hs)[t + 256] = hsrc[t + 256];
    __syncthreads();

    int ln = t >> 4, dim = t & 15;
    int n = blockIdx.x * 16 + ln;      // N divisible by 16
    float dot = 0.f;
    const float4* hrow = (const float4*)(hs + ln * F1);
    #pragma unroll 8
    for (int k4 = 0; k4 < 32; k4++){
        float4 hv = hrow[k4];
        int k = k4 * 4;
        dot += hv.x * W2s[(k    ) * 16 + dim];
        dot += hv.y * W2s[(k + 1) * 16 + dim];
        dot += hv.z * W2s[(k + 2) * 16 + dim];
        dot += hv.w * W2s[(k + 3) * 16 + dim];
    }
    float ps = dot * as2w[dim];
    float pd = dot * ad2w[dim];
    #pragma unroll
    for (int off = 8; off >= 1; off >>= 1){
        ps += __shfl_down(ps, off, 16);
        pd += __shfl_down(pd, off, 16);
    }
    if (dim == 0){ a_s2[n] = ps; a_d2[n] = pd; }
    h2h[(size_t)n * 16 + dim] = __float2half(dot);
}

// ---------------- Layer 2 aggregate + classifier: one wave per node, 4 edge-groups x 16 dims ----------------
__global__ __launch_bounds__(256) void k_agg2(
    const __half* __restrict__ h2h, const float* __restrict__ a_s2, const float* __restrict__ a_d2,
    const int* __restrict__ row_ptr, const int* __restrict__ esrc,
    const float* __restrict__ b2, const float* __restrict__ Wc1, const float* __restrict__ bc1,
    const float* __restrict__ Wc2, const float* __restrict__ bc2, float* __restrict__ out){
    int t = threadIdx.x;
    int wv = t >> 6, lane = t & 63;
    int n = blockIdx.x * 4 + wv;       // N divisible by 4
    int g = lane >> 4;                 // edge subgroup (0..3)
    int d = lane & 15;                 // dim
    float adn = a_d2[n], asn = a_s2[n];

    float den = 0.f, acc = 0.f;
    if (g == 0){
        float w = __expf(leaky(asn + adn));
        den = w;
        acc = w * __half2float(h2h[(size_t)n * 16 + d]);
    }
    int start = row_ptr[n], end = row_ptr[n + 1];
    for (int i = start + g; i < end; i += 4){
        int s = esrc[i];
        float w = __expf(leaky(a_s2[s] + adn));
        den += w;
        acc += w * __half2float(h2h[(size_t)s * 16 + d]);
    }
    den += __shfl_xor(den, 16); den += __shfl_xor(den, 32);
    acc += __shfl_xor(acc, 16); acc += __shfl_xor(acc, 32);
    float embv = elu1(acc / (den + 1e-16f) + b2[d]);
    if (g == 0) out[(size_t)n * 16 + d] = embv;

    // classifier: every 8-lane group redundantly computes one hidden unit set
    int sub = lane & 7;
    float hid = bc1[sub];
    #pragma unroll
    for (int dd = 0; dd < 16; dd++)
        hid += __shfl(embv, dd, 64) * Wc1[dd * 8 + sub];
    float contrib = fmaxf(hid, 0.f) * Wc2[sub];
    contrib += __shfl_xor(contrib, 1);
    contrib += __shfl_xor(contrib, 2);
    contrib += __shfl_xor(contrib, 4);
    if (lane == 0) out[(size_t)N_NODES * 16 + n] = 1.f / (1.f + __expf(-(contrib + bc2[0])));
}

extern "C" void kernel_launch(void* const* d_in, const int* in_sizes, int n_in,
                              void* d_out, int out_size, void* d_ws, size_t ws_size,
                              hipStream_t stream){
    const float* x    = (const float*)d_in[0];
    const int*   ei   = (const int*)d_in[1];
    const float* W1   = (const float*)d_in[2];
    const float* as1w = (const float*)d_in[3];
    const float* ad1w = (const float*)d_in[4];
    const float* b1   = (const float*)d_in[5];
    const float* W2   = (const float*)d_in[6];
    const float* as2w = (const float*)d_in[7];
    const float* ad2w = (const float*)d_in[8];
    const float* b2   = (const float*)d_in[9];
    const float* Wc1  = (const float*)d_in[10];
    const float* bc1  = (const float*)d_in[11];
    const float* Wc2  = (const float*)d_in[12];
    const float* bc2  = (const float*)d_in[13];
    float* out = (float*)d_out;
    const int* src = ei;
    const int* dst = ei + N_EDGES;

    float* ws   = (float*)d_ws;
    float* hL1  = ws;                                   // N*128 f32
    float* a_s1 = hL1 + (size_t)N_NODES * F1;           // N*4
    float* a_d1 = a_s1 + (size_t)N_NODES * 4;           // N*4
    float* a_s2 = a_d1 + (size_t)N_NODES * 4;           // N
    float* a_d2 = a_s2 + N_NODES;                       // N
    __half* h1h = (__half*)(a_d2 + N_NODES);            // N*128 f16
    __half* h2h = h1h + (size_t)N_NODES * F1;           // N*16 f16
    int* deg      = (int*)(h2h + (size_t)N_NODES * 16); // N
    int* row_ptr  = deg + N_NODES;                      // N+1
    int* cursor   = row_ptr + N_NODES + 1;              // N
    int* chunkOff = cursor + N_NODES;                   // 128
    int* esrc     = chunkOff + 128;                     // E

    hipMemsetAsync(deg, 0, N_NODES * sizeof(int), stream);
    int nchunks = (N_NODES + SCAN_CHUNK - 1) / SCAN_CHUNK;   // 98
    k_count<<<N_EDGES / 256, 256, 0, stream>>>(dst, deg);
    k_chunk_sums<<<nchunks, 256, 0, stream>>>(deg, chunkOff);
    k_scan_offsets<<<1, 128, 0, stream>>>(chunkOff, nchunks);
    k_scan_final<<<nchunks, 256, 0, stream>>>(deg, chunkOff, row_ptr, cursor);
    k_fill<<<N_EDGES / 256, 256, 0, stream>>>(src, dst, cursor, esrc);

    k_dense1<<<N_NODES / 8, 256, 0, stream>>>(x, W1, as1w, ad1w, h1h, a_s1, a_d1);
    k_agg1<<<N_NODES / 4, 256, 0, stream>>>(h1h, a_s1, a_d1, row_ptr, esrc, b1, hL1);
    k_dense2<<<N_NODES / 16, 256, 0, stream>>>(hL1, W2, as2w, ad2w, h2h, a_s2, a_d2);
    k_agg2<<<N_NODES / 4, 256, 0, stream>>>(h2h, a_s2, a_d2, row_ptr, esrc, b2, Wc1, bc1, Wc2, bc2, out);
}

// Round 3
// 321.812 us; speedup vs baseline: 1.8289x; 1.4801x over previous
//
#include <hip/hip_runtime.h>
#include <hip/hip_fp16.h>
#include <math.h>

#define N_NODES 100000
#define N_EDGES 1600000
#define F_IN 8
#define HID 32
#define HEADS 4
#define F1 128    // HEADS*HID
#define F2 16     // OUT
#define NB 98        // coarse buckets of 1024 nodes
#define BCAP 20480   // per-bucket capacity (mean ~16384, sd ~127 -> 32 sigma headroom)

__device__ __forceinline__ float leaky(float x){ return x > 0.f ? x : 0.2f * x; }
__device__ __forceinline__ float elu1(float x){ return x > 0.f ? x : __expf(x) - 1.f; }

// ---------------- CSR build: two-level counting sort ----------------
// Pass 1: bin edges into 98 coarse buckets (1024 nodes each) with line-local writes.
__global__ __launch_bounds__(256) void k_bin_fill(
    const int* __restrict__ src, const int* __restrict__ dst,
    int* __restrict__ bucketCnt, unsigned int* __restrict__ ebuf){
    __shared__ int hist[NB];
    __shared__ int basePos[NB];
    __shared__ int cur[NB];
    int t = threadIdx.x;
    if (t < NB) hist[t] = 0;
    __syncthreads();
    int base = blockIdx.x * 4096;
    #pragma unroll
    for (int j = 0; j < 16; j++){
        int e = base + j * 256 + t;
        if (e < N_EDGES) atomicAdd(&hist[dst[e] >> 10], 1);
    }
    __syncthreads();
    if (t < NB){
        basePos[t] = atomicAdd(&bucketCnt[t], hist[t]);
        cur[t] = 0;
    }
    __syncthreads();
    #pragma unroll
    for (int j = 0; j < 16; j++){
        int e = base + j * 256 + t;
        if (e < N_EDGES){
            int d = dst[e];
            int b = d >> 10;
            int off = atomicAdd(&cur[b], 1);
            ebuf[b * BCAP + basePos[b] + off] = ((unsigned)(d & 1023) << 17) | (unsigned)src[e];
        }
    }
}

// Pass 2: one block per bucket -> local degree count, LDS scan, exact CSR.
// Absorbs the old k_count + 3 scan kernels; esrc writes stay in one 65KB region.
__global__ __launch_bounds__(1024) void k_local_csr(
    const int* __restrict__ bucketCnt, const unsigned int* __restrict__ ebuf,
    int* __restrict__ row_ptr, int* __restrict__ esrc){
    __shared__ int deg[1024];
    __shared__ int scn[1024];
    __shared__ int cntAll[NB];
    __shared__ int sbase;
    int b = blockIdx.x, t = threadIdx.x;
    deg[t] = 0;
    if (t < NB) cntAll[t] = bucketCnt[t];
    __syncthreads();
    if (t == 0){
        int s = 0;
        for (int i = 0; i < b; i++) s += cntAll[i];
        sbase = s;
    }
    int cnt = cntAll[b];
    const unsigned int* seg = ebuf + b * BCAP;
    for (int i = t; i < cnt; i += 1024)
        atomicAdd(&deg[seg[i] >> 17], 1);
    __syncthreads();
    int v = deg[t];
    scn[t] = v;
    __syncthreads();
    for (int off = 1; off < 1024; off <<= 1){
        int x = (t >= off) ? scn[t - off] : 0;
        __syncthreads();
        scn[t] += x;
        __syncthreads();
    }
    int excl = scn[t] - v;
    int start = sbase + excl;
    int n = b * 1024 + t;
    if (n < N_NODES) row_ptr[n] = start;
    if (b == NB - 1 && t == 0) row_ptr[N_NODES] = sbase + cnt;
    deg[t] = start;            // reuse as global cursor
    __syncthreads();
    for (int i = t; i < cnt; i += 1024){
        unsigned int e = seg[i];
        int pos = atomicAdd(&deg[e >> 17], 1);
        esrc[pos] = (int)(e & 0x1FFFFu);
    }
}

// ---------------- Layer 1 dense: h1 = x@W1 (fp16 out) ; a_s1/a_d1 per head ----------------
__global__ __launch_bounds__(256) void k_dense1(
    const float* __restrict__ x, const float* __restrict__ W1,
    const float* __restrict__ as1w, const float* __restrict__ ad1w,
    __half* __restrict__ h1h, float* __restrict__ a_s1, float* __restrict__ a_d1){
    __shared__ float W1s[F_IN * F1];          // 1024
    __shared__ float atts[HEADS * HID];       // 128
    __shared__ float attd[HEADS * HID];       // 128
    __shared__ float xs[8 * F_IN];            // 64
    int t = threadIdx.x;
    ((float4*)W1s)[t] = ((const float4*)W1)[t];        // 256 * 4 = 1024 floats
    if (t < 128){ atts[t] = as1w[t]; attd[t] = ad1w[t]; }
    if (t < 64) xs[t] = x[blockIdx.x * 64 + t];
    __syncthreads();

    int ln = t >> 5, l32 = t & 31;
    int n = blockIdx.x * 8 + ln;               // N divisible by 8
    float xr[8];
    #pragma unroll
    for (int k = 0; k < 8; k++) xr[k] = xs[ln * 8 + k];
    int j0 = l32 * 4;
    float o0 = 0, o1 = 0, o2 = 0, o3 = 0;
    #pragma unroll
    for (int k = 0; k < 8; k++){
        float4 w4 = ((const float4*)(W1s + k * F1))[l32];
        o0 += xr[k] * w4.x; o1 += xr[k] * w4.y; o2 += xr[k] * w4.z; o3 += xr[k] * w4.w;
    }
    int hd = l32 >> 3;
    int dl = j0 & 31;
    float ps = o0 * atts[hd * 32 + dl] + o1 * atts[hd * 32 + dl + 1]
             + o2 * atts[hd * 32 + dl + 2] + o3 * atts[hd * 32 + dl + 3];
    float pd = o0 * attd[hd * 32 + dl] + o1 * attd[hd * 32 + dl + 1]
             + o2 * attd[hd * 32 + dl + 2] + o3 * attd[hd * 32 + dl + 3];
    ps += __shfl_down(ps, 4, 8); ps += __shfl_down(ps, 2, 8); ps += __shfl_down(ps, 1, 8);
    pd += __shfl_down(pd, 4, 8); pd += __shfl_down(pd, 2, 8); pd += __shfl_down(pd, 1, 8);
    if ((l32 & 7) == 0){ a_s1[n * 4 + hd] = ps; a_d1[n * 4 + hd] = pd; }
    __half2* hp = (__half2*)(h1h + (size_t)n * F1 + j0);
    hp[0] = __floats2half2_rn(o0, o1);
    hp[1] = __floats2half2_rn(o2, o3);
}

// ---------------- Layer 1 aggregate: one wave per node, 2 edge-groups x 32 dim-lanes ----------------
__global__ __launch_bounds__(256) void k_agg1(
    const __half* __restrict__ h1h, const float* __restrict__ a_s1, const float* __restrict__ a_d1,
    const int* __restrict__ row_ptr, const int* __restrict__ esrc,
    const float* __restrict__ b1, float* __restrict__ hL1){
    int t = threadIdx.x;
    int wv = t >> 6, lane = t & 63;
    int n = blockIdx.x * 4 + wv;               // N divisible by 4
    int g = lane >> 5;                          // edge subgroup (0/1)
    int l = lane & 31;                          // dim-lane: owns dims 4l..4l+3
    int d0 = l * 4;
    int hd = l >> 3;                            // head for these dims

    float adh = a_d1[n * 4 + hd];
    float ash = a_s1[n * 4 + hd];

    float den = 0.f, acc0 = 0.f, acc1 = 0.f, acc2 = 0.f, acc3 = 0.f;
    if (g == 0){
        // self-loop (softmax shift m=0: logits are O(1), no overflow risk)
        float w = __expf(leaky(ash + adh));
        den = w;
        const __half2* hp = (const __half2*)(h1h + (size_t)n * F1 + d0);
        __half2 p01 = hp[0], p23 = hp[1];
        acc0 = w * __low2float(p01); acc1 = w * __high2float(p01);
        acc2 = w * __low2float(p23); acc3 = w * __high2float(p23);
    }
    int start = row_ptr[n], end = row_ptr[n + 1];
    int i = start + g;
    int lim = end - 2;                          // i and i+2 both valid while i < lim
    for (; i < lim; i += 4){
        int s0 = esrc[i], s1 = esrc[i + 2];
        float e0 = a_s1[s0 * 4 + hd];
        float e1 = a_s1[s1 * 4 + hd];
        const __half2* hp0 = (const __half2*)(h1h + (size_t)s0 * F1 + d0);
        const __half2* hp1 = (const __half2*)(h1h + (size_t)s1 * F1 + d0);
        __half2 a01 = hp0[0], a23 = hp0[1];
        __half2 b01 = hp1[0], b23 = hp1[1];
        float w0 = __expf(leaky(e0 + adh));
        float w1 = __expf(leaky(e1 + adh));
        den += w0 + w1;
        acc0 += w0 * __low2float(a01) + w1 * __low2float(b01);
        acc1 += w0 * __high2float(a01) + w1 * __high2float(b01);
        acc2 += w0 * __low2float(a23) + w1 * __low2float(b23);
        acc3 += w0 * __high2float(a23) + w1 * __high2float(b23);
    }
    if (i < end){
        int s0 = esrc[i];
        float w0 = __expf(leaky(a_s1[s0 * 4 + hd] + adh));
        const __half2* hp0 = (const __half2*)(h1h + (size_t)s0 * F1 + d0);
        __half2 a01 = hp0[0], a23 = hp0[1];
        den += w0;
        acc0 += w0 * __low2float(a01); acc1 += w0 * __high2float(a01);
        acc2 += w0 * __low2float(a23); acc3 += w0 * __high2float(a23);
    }
    // combine the two edge-groups (paired lanes share d0/hd)
    den  += __shfl_xor(den, 32);
    acc0 += __shfl_xor(acc0, 32);
    acc1 += __shfl_xor(acc1, 32);
    acc2 += __shfl_xor(acc2, 32);
    acc3 += __shfl_xor(acc3, 32);
    if (g == 0){
        float inv = 1.f / (den + 1e-16f);
        float4 b4 = *(const float4*)(b1 + d0);
        float4 ov;
        ov.x = elu1(acc0 * inv + b4.x);
        ov.y = elu1(acc1 * inv + b4.y);
        ov.z = elu1(acc2 * inv + b4.z);
        ov.w = elu1(acc3 * inv + b4.w);
        *(float4*)(hL1 + (size_t)n * F1 + d0) = ov;
    }
}

// ---------------- Layer 2 dense: h2 = hL1@W2 (fp16 out) ; a_s2/a_d2 ----------------
__global__ __launch_bounds__(256) void k_dense2(
    const float* __restrict__ hL1, const float* __restrict__ W2,
    const float* __restrict__ as2w, const float* __restrict__ ad2w,
    __half* __restrict__ h2h, float* __restrict__ a_s2, float* __restrict__ a_d2){
    __shared__ float W2s[F1 * F2];    // 2048
    __shared__ float hs[16 * F1];     // 2048
    int t = threadIdx.x;
    ((float4*)W2s)[t]       = ((const float4*)W2)[t];
    ((float4*)W2s)[t + 256] = ((const float4*)W2)[t + 256];
    const float4* hsrc = (const float4*)(hL1 + (size_t)blockIdx.x * 16 * F1);
    ((float4*)hs)[t]       = hsrc[t];
    ((float4*)hs)[t + 256] = hsrc[t + 256];
    __syncthreads();

    int ln = t >> 4, dim = t & 15;
    int n = blockIdx.x * 16 + ln;      // N divisible by 16
    float dot = 0.f;
    const float4* hrow = (const float4*)(hs + ln * F1);
    #pragma unroll 8
    for (int k4 = 0; k4 < 32; k4++){
        float4 hv = hrow[k4];
        int k = k4 * 4;
        dot += hv.x * W2s[(k    ) * 16 + dim];
        dot += hv.y * W2s[(k + 1) * 16 + dim];
        dot += hv.z * W2s[(k + 2) * 16 + dim];
        dot += hv.w * W2s[(k + 3) * 16 + dim];
    }
    float ps = dot * as2w[dim];
    float pd = dot * ad2w[dim];
    #pragma unroll
    for (int off = 8; off >= 1; off >>= 1){
        ps += __shfl_down(ps, off, 16);
        pd += __shfl_down(pd, off, 16);
    }
    if (dim == 0){ a_s2[n] = ps; a_d2[n] = pd; }
    h2h[(size_t)n * 16 + dim] = __float2half(dot);
}

// ---------------- Layer 2 aggregate + classifier: one wave per node, 4 edge-groups x 16 dims ----------------
__global__ __launch_bounds__(256) void k_agg2(
    const __half* __restrict__ h2h, const float* __restrict__ a_s2, const float* __restrict__ a_d2,
    const int* __restrict__ row_ptr, const int* __restrict__ esrc,
    const float* __restrict__ b2, const float* __restrict__ Wc1, const float* __restrict__ bc1,
    const float* __restrict__ Wc2, const float* __restrict__ bc2, float* __restrict__ out){
    int t = threadIdx.x;
    int wv = t >> 6, lane = t & 63;
    int n = blockIdx.x * 4 + wv;       // N divisible by 4
    int g = lane >> 4;                 // edge subgroup (0..3)
    int d = lane & 15;                 // dim
    float adn = a_d2[n], asn = a_s2[n];

    float den = 0.f, acc = 0.f;
    if (g == 0){
        float w = __expf(leaky(asn + adn));
        den = w;
        acc = w * __half2float(h2h[(size_t)n * 16 + d]);
    }
    int start = row_ptr[n], end = row_ptr[n + 1];
    for (int i = start + g; i < end; i += 4){
        int s = esrc[i];
        float w = __expf(leaky(a_s2[s] + adn));
        den += w;
        acc += w * __half2float(h2h[(size_t)s * 16 + d]);
    }
    den += __shfl_xor(den, 16); den += __shfl_xor(den, 32);
    acc += __shfl_xor(acc, 16); acc += __shfl_xor(acc, 32);
    float embv = elu1(acc / (den + 1e-16f) + b2[d]);
    if (g == 0) out[(size_t)n * 16 + d] = embv;

    // classifier: every 8-lane group redundantly computes one hidden unit set
    int sub = lane & 7;
    float hid = bc1[sub];
    #pragma unroll
    for (int dd = 0; dd < 16; dd++)
        hid += __shfl(embv, dd, 64) * Wc1[dd * 8 + sub];
    float contrib = fmaxf(hid, 0.f) * Wc2[sub];
    contrib += __shfl_xor(contrib, 1);
    contrib += __shfl_xor(contrib, 2);
    contrib += __shfl_xor(contrib, 4);
    if (lane == 0) out[(size_t)N_NODES * 16 + n] = 1.f / (1.f + __expf(-(contrib + bc2[0])));
}

extern "C" void kernel_launch(void* const* d_in, const int* in_sizes, int n_in,
                              void* d_out, int out_size, void* d_ws, size_t ws_size,
                              hipStream_t stream){
    const float* x    = (const float*)d_in[0];
    const int*   ei   = (const int*)d_in[1];
    const float* W1   = (const float*)d_in[2];
    const float* as1w = (const float*)d_in[3];
    const float* ad1w = (const float*)d_in[4];
    const float* b1   = (const float*)d_in[5];
    const float* W2   = (const float*)d_in[6];
    const float* as2w = (const float*)d_in[7];
    const float* ad2w = (const float*)d_in[8];
    const float* b2   = (const float*)d_in[9];
    const float* Wc1  = (const float*)d_in[10];
    const float* bc1  = (const float*)d_in[11];
    const float* Wc2  = (const float*)d_in[12];
    const float* bc2  = (const float*)d_in[13];
    float* out = (float*)d_out;
    const int* src = ei;
    const int* dst = ei + N_EDGES;

    float* ws   = (float*)d_ws;
    float* hL1  = ws;                                   // N*128 f32
    float* a_s1 = hL1 + (size_t)N_NODES * F1;           // N*4
    float* a_d1 = a_s1 + (size_t)N_NODES * 4;           // N*4
    float* a_s2 = a_d1 + (size_t)N_NODES * 4;           // N
    float* a_d2 = a_s2 + N_NODES;                       // N
    __half* h1h = (__half*)(a_d2 + N_NODES);            // N*128 f16
    __half* h2h = h1h + (size_t)N_NODES * F1;           // N*16 f16
    int* bucketCnt = (int*)(h2h + (size_t)N_NODES * 16);// NB
    int* row_ptr  = bucketCnt + NB;                     // N+1
    int* esrc     = row_ptr + N_NODES + 1;              // E
    unsigned int* ebuf = (unsigned int*)(esrc + N_EDGES); // NB*BCAP

    hipMemsetAsync(bucketCnt, 0, NB * sizeof(int), stream);
    k_bin_fill<<<(N_EDGES + 4095) / 4096, 256, 0, stream>>>(src, dst, bucketCnt, ebuf);
    k_local_csr<<<NB, 1024, 0, stream>>>(bucketCnt, ebuf, row_ptr, esrc);

    k_dense1<<<N_NODES / 8, 256, 0, stream>>>(x, W1, as1w, ad1w, h1h, a_s1, a_d1);
    k_agg1<<<N_NODES / 4, 256, 0, stream>>>(h1h, a_s1, a_d1, row_ptr, esrc, b1, hL1);
    k_dense2<<<N_NODES / 16, 256, 0, stream>>>(hL1, W2, as2w, ad2w, h2h, a_s2, a_d2);
    k_agg2<<<N_NODES / 4, 256, 0, stream>>>(h2h, a_s2, a_d2, row_ptr, esrc, b2, Wc1, bc1, Wc2, bc2, out);
}

// Round 4
// 299.363 us; speedup vs baseline: 1.9661x; 1.0750x over previous
//
#include <hip/hip_runtime.h>
#include <hip/hip_fp16.h>
#include <math.h>

#define N_NODES 100000
#define N_EDGES 1600000
#define F_IN 8
#define HID 32
#define HEADS 4
#define F1 128    // HEADS*HID
#define F2 16     // OUT
#define NB 98        // coarse buckets of 1024 nodes
#define BCAP 20480   // per-bucket capacity (mean ~16384, sd ~127 -> 32 sigma headroom)

__device__ __forceinline__ float leaky(float x){ return x > 0.f ? x : 0.2f * x; }
__device__ __forceinline__ float elu1(float x){ return x > 0.f ? x : __expf(x) - 1.f; }

__device__ __forceinline__ void fma8(float* acc, float w, const uint4& r){
    const __half2* p = (const __half2*)&r;
    #pragma unroll
    for (int k = 0; k < 4; k++){
        float2 f = __half22float2(p[k]);
        acc[2 * k]     += w * f.x;
        acc[2 * k + 1] += w * f.y;
    }
}

// ---------------- CSR build: two-level counting sort ----------------
__global__ __launch_bounds__(256) void k_bin_fill(
    const int* __restrict__ src, const int* __restrict__ dst,
    int* __restrict__ bucketCnt, unsigned int* __restrict__ ebuf){
    __shared__ int hist[NB];
    __shared__ int basePos[NB];
    __shared__ int cur[NB];
    int t = threadIdx.x;
    if (t < NB) hist[t] = 0;
    __syncthreads();
    int base = blockIdx.x * 4096;
    #pragma unroll
    for (int j = 0; j < 16; j++){
        int e = base + j * 256 + t;
        if (e < N_EDGES) atomicAdd(&hist[dst[e] >> 10], 1);
    }
    __syncthreads();
    if (t < NB){
        basePos[t] = atomicAdd(&bucketCnt[t], hist[t]);
        cur[t] = 0;
    }
    __syncthreads();
    #pragma unroll
    for (int j = 0; j < 16; j++){
        int e = base + j * 256 + t;
        if (e < N_EDGES){
            int d = dst[e];
            int b = d >> 10;
            int off = atomicAdd(&cur[b], 1);
            ebuf[b * BCAP + basePos[b] + off] = ((unsigned)(d & 1023) << 17) | (unsigned)src[e];
        }
    }
}

__global__ __launch_bounds__(1024) void k_local_csr(
    const int* __restrict__ bucketCnt, const unsigned int* __restrict__ ebuf,
    int* __restrict__ row_ptr, int* __restrict__ esrc){
    __shared__ int deg[1024];
    __shared__ int scn[1024];
    __shared__ int cntAll[NB];
    __shared__ int sbase;
    int b = blockIdx.x, t = threadIdx.x;
    deg[t] = 0;
    if (t < NB) cntAll[t] = bucketCnt[t];
    __syncthreads();
    if (t == 0){
        int s = 0;
        for (int i = 0; i < b; i++) s += cntAll[i];
        sbase = s;
    }
    int cnt = cntAll[b];
    const unsigned int* seg = ebuf + b * BCAP;
    for (int i = t; i < cnt; i += 1024)
        atomicAdd(&deg[seg[i] >> 17], 1);
    __syncthreads();
    int v = deg[t];
    scn[t] = v;
    __syncthreads();
    for (int off = 1; off < 1024; off <<= 1){
        int x = (t >= off) ? scn[t - off] : 0;
        __syncthreads();
        scn[t] += x;
        __syncthreads();
    }
    int excl = scn[t] - v;
    int start = sbase + excl;
    int n = b * 1024 + t;
    if (n < N_NODES) row_ptr[n] = start;
    if (b == NB - 1 && t == 0) row_ptr[N_NODES] = sbase + cnt;
    deg[t] = start;            // reuse as global cursor
    __syncthreads();
    for (int i = t; i < cnt; i += 1024){
        unsigned int e = seg[i];
        int pos = atomicAdd(&deg[e >> 17], 1);
        esrc[pos] = (int)(e & 0x1FFFFu);
    }
}

// ---------------- Layer 1 dense: h1 = x@W1 (fp16 out) ; a_s1/a_d1 per head ----------------
__global__ __launch_bounds__(256) void k_dense1(
    const float* __restrict__ x, const float* __restrict__ W1,
    const float* __restrict__ as1w, const float* __restrict__ ad1w,
    __half* __restrict__ h1h, float* __restrict__ a_s1, float* __restrict__ a_d1){
    __shared__ float W1s[F_IN * F1];          // 1024
    __shared__ float atts[HEADS * HID];       // 128
    __shared__ float attd[HEADS * HID];       // 128
    __shared__ float xs[8 * F_IN];            // 64
    int t = threadIdx.x;
    ((float4*)W1s)[t] = ((const float4*)W1)[t];        // 256 * 4 = 1024 floats
    if (t < 128){ atts[t] = as1w[t]; attd[t] = ad1w[t]; }
    if (t < 64) xs[t] = x[blockIdx.x * 64 + t];
    __syncthreads();

    int ln = t >> 5, l32 = t & 31;
    int n = blockIdx.x * 8 + ln;               // N divisible by 8
    float xr[8];
    #pragma unroll
    for (int k = 0; k < 8; k++) xr[k] = xs[ln * 8 + k];
    int j0 = l32 * 4;
    float o0 = 0, o1 = 0, o2 = 0, o3 = 0;
    #pragma unroll
    for (int k = 0; k < 8; k++){
        float4 w4 = ((const float4*)(W1s + k * F1))[l32];
        o0 += xr[k] * w4.x; o1 += xr[k] * w4.y; o2 += xr[k] * w4.z; o3 += xr[k] * w4.w;
    }
    int hd = l32 >> 3;
    int dl = j0 & 31;
    float ps = o0 * atts[hd * 32 + dl] + o1 * atts[hd * 32 + dl + 1]
             + o2 * atts[hd * 32 + dl + 2] + o3 * atts[hd * 32 + dl + 3];
    float pd = o0 * attd[hd * 32 + dl] + o1 * attd[hd * 32 + dl + 1]
             + o2 * attd[hd * 32 + dl + 2] + o3 * attd[hd * 32 + dl + 3];
    ps += __shfl_down(ps, 4, 8); ps += __shfl_down(ps, 2, 8); ps += __shfl_down(ps, 1, 8);
    pd += __shfl_down(pd, 4, 8); pd += __shfl_down(pd, 2, 8); pd += __shfl_down(pd, 1, 8);
    if ((l32 & 7) == 0){ a_s1[n * 4 + hd] = ps; a_d1[n * 4 + hd] = pd; }
    __half2* hp = (__half2*)(h1h + (size_t)n * F1 + j0);
    hp[0] = __floats2half2_rn(o0, o1);
    hp[1] = __floats2half2_rn(o2, o3);
}

// ---------------- Layer 1 aggregate: one wave per node, 4 edge-groups x 16 lanes x 8 dims ----------------
__global__ __launch_bounds__(256) void k_agg1(
    const __half* __restrict__ h1h, const float* __restrict__ a_s1, const float* __restrict__ a_d1,
    const int* __restrict__ row_ptr, const int* __restrict__ esrc,
    const float* __restrict__ b1, float* __restrict__ hL1){
    int t = threadIdx.x;
    int wv = t >> 6, lane = t & 63;
    int n = blockIdx.x * 4 + wv;               // N divisible by 4
    int g = lane >> 4;                          // edge subgroup (0..3)
    int l = lane & 15;                          // owns dims 8l..8l+7
    int hd = l >> 2;                            // head for these dims

    float adh = a_d1[n * 4 + hd];
    float den = 0.f;
    float acc[8];
    #pragma unroll
    for (int k = 0; k < 8; k++) acc[k] = 0.f;

    if (g == 0){
        // self-loop (softmax shift m=0: logits are O(1), no overflow risk)
        float w = __expf(leaky(a_s1[n * 4 + hd] + adh));
        den = w;
        uint4 r = *(const uint4*)(h1h + (size_t)n * F1 + l * 8);
        fma8(acc, w, r);
    }
    int start = row_ptr[n], end = row_ptr[n + 1];
    int i = start + g;
    for (; i + 4 < end; i += 8){
        int s0 = esrc[i], s1 = esrc[i + 4];
        float e0 = a_s1[s0 * 4 + hd];
        float e1 = a_s1[s1 * 4 + hd];
        uint4 r0 = *(const uint4*)(h1h + (size_t)s0 * F1 + l * 8);
        uint4 r1 = *(const uint4*)(h1h + (size_t)s1 * F1 + l * 8);
        float w0 = __expf(leaky(e0 + adh));
        float w1 = __expf(leaky(e1 + adh));
        den += w0 + w1;
        fma8(acc, w0, r0);
        fma8(acc, w1, r1);
    }
    if (i < end){
        int s0 = esrc[i];
        float w0 = __expf(leaky(a_s1[s0 * 4 + hd] + adh));
        uint4 r0 = *(const uint4*)(h1h + (size_t)s0 * F1 + l * 8);
        den += w0;
        fma8(acc, w0, r0);
    }
    // combine the four edge-groups (lanes xor16/xor32 share l, hd)
    den += __shfl_xor(den, 16); den += __shfl_xor(den, 32);
    #pragma unroll
    for (int k = 0; k < 8; k++){
        acc[k] += __shfl_xor(acc[k], 16);
        acc[k] += __shfl_xor(acc[k], 32);
    }
    if (g == 0){
        float inv = 1.f / (den + 1e-16f);
        int d0 = l * 8;
        float4 ba = *(const float4*)(b1 + d0);
        float4 bb = *(const float4*)(b1 + d0 + 4);
        float4 oa, ob;
        oa.x = elu1(acc[0] * inv + ba.x);
        oa.y = elu1(acc[1] * inv + ba.y);
        oa.z = elu1(acc[2] * inv + ba.z);
        oa.w = elu1(acc[3] * inv + ba.w);
        ob.x = elu1(acc[4] * inv + bb.x);
        ob.y = elu1(acc[5] * inv + bb.y);
        ob.z = elu1(acc[6] * inv + bb.z);
        ob.w = elu1(acc[7] * inv + bb.w);
        *(float4*)(hL1 + (size_t)n * F1 + d0) = oa;
        *(float4*)(hL1 + (size_t)n * F1 + d0 + 4) = ob;
    }
}

// ---------------- Layer 2 dense: h2 = hL1@W2 (fp16 out) ; a_s2/a_d2 ----------------
__global__ __launch_bounds__(256) void k_dense2(
    const float* __restrict__ hL1, const float* __restrict__ W2,
    const float* __restrict__ as2w, const float* __restrict__ ad2w,
    __half* __restrict__ h2h, float* __restrict__ a_s2, float* __restrict__ a_d2){
    __shared__ float W2s[F1 * F2];    // 2048
    __shared__ float hs[16 * F1];     // 2048
    int t = threadIdx.x;
    ((float4*)W2s)[t]       = ((const float4*)W2)[t];
    ((float4*)W2s)[t + 256] = ((const float4*)W2)[t + 256];
    const float4* hsrc = (const float4*)(hL1 + (size_t)blockIdx.x * 16 * F1);
    ((float4*)hs)[t]       = hsrc[t];
    ((float4*)hs)[t + 256] = hsrc[t + 256];
    __syncthreads();

    int ln = t >> 4, dim = t & 15;
    int n = blockIdx.x * 16 + ln;      // N divisible by 16
    float dot = 0.f;
    const float4* hrow = (const float4*)(hs + ln * F1);
    #pragma unroll 8
    for (int k4 = 0; k4 < 32; k4++){
        float4 hv = hrow[k4];
        int k = k4 * 4;
        dot += hv.x * W2s[(k    ) * 16 + dim];
        dot += hv.y * W2s[(k + 1) * 16 + dim];
        dot += hv.z * W2s[(k + 2) * 16 + dim];
        dot += hv.w * W2s[(k + 3) * 16 + dim];
    }
    float ps = dot * as2w[dim];
    float pd = dot * ad2w[dim];
    #pragma unroll
    for (int off = 8; off >= 1; off >>= 1){
        ps += __shfl_down(ps, off, 16);
        pd += __shfl_down(pd, off, 16);
    }
    if (dim == 0){ a_s2[n] = ps; a_d2[n] = pd; }
    h2h[(size_t)n * 16 + dim] = __float2half(dot);
}

// ---------------- Layer 2 aggregate + classifier: 8 edge-groups x 8 lanes x 2 dims ----------------
__global__ __launch_bounds__(256) void k_agg2(
    const __half* __restrict__ h2h, const float* __restrict__ a_s2, const float* __restrict__ a_d2,
    const int* __restrict__ row_ptr, const int* __restrict__ esrc,
    const float* __restrict__ b2, const float* __restrict__ Wc1, const float* __restrict__ bc1,
    const float* __restrict__ Wc2, const float* __restrict__ bc2, float* __restrict__ out){
    int t = threadIdx.x;
    int wv = t >> 6, lane = t & 63;
    int n = blockIdx.x * 4 + wv;       // N divisible by 4
    int g = lane >> 3;                 // edge subgroup (0..7)
    int l = lane & 7;                  // owns dims 2l, 2l+1
    float adn = a_d2[n];

    float den = 0.f, acc0 = 0.f, acc1 = 0.f;
    if (g == 0){
        float w = __expf(leaky(a_s2[n] + adn));
        den = w;
        float2 f = __half22float2(*(const __half2*)(h2h + (size_t)n * 16 + 2 * l));
        acc0 = w * f.x; acc1 = w * f.y;
    }
    int start = row_ptr[n], end = row_ptr[n + 1];
    int i = start + g;
    for (; i + 8 < end; i += 16){
        int s0 = esrc[i], s1 = esrc[i + 8];
        float e0 = a_s2[s0], e1 = a_s2[s1];
        __half2 p0 = *(const __half2*)(h2h + (size_t)s0 * 16 + 2 * l);
        __half2 p1 = *(const __half2*)(h2h + (size_t)s1 * 16 + 2 * l);
        float w0 = __expf(leaky(e0 + adn));
        float w1 = __expf(leaky(e1 + adn));
        den += w0 + w1;
        float2 f0 = __half22float2(p0), f1 = __half22float2(p1);
        acc0 += w0 * f0.x + w1 * f1.x;
        acc1 += w0 * f0.y + w1 * f1.y;
    }
    if (i < end){
        int s0 = esrc[i];
        float w0 = __expf(leaky(a_s2[s0] + adn));
        float2 f0 = __half22float2(*(const __half2*)(h2h + (size_t)s0 * 16 + 2 * l));
        den += w0;
        acc0 += w0 * f0.x; acc1 += w0 * f0.y;
    }
    #pragma unroll
    for (int off = 8; off <= 32; off <<= 1){
        den  += __shfl_xor(den, off);
        acc0 += __shfl_xor(acc0, off);
        acc1 += __shfl_xor(acc1, off);
    }
    float inv = 1.f / (den + 1e-16f);
    float e0v = elu1(acc0 * inv + b2[2 * l]);
    float e1v = elu1(acc1 * inv + b2[2 * l + 1]);
    if (g == 0){
        float2 ov; ov.x = e0v; ov.y = e1v;
        *(float2*)(out + (size_t)n * 16 + 2 * l) = ov;
    }
    // classifier: each 8-lane cluster computes the full hidden layer redundantly
    float hid = bc1[l];
    #pragma unroll
    for (int j = 0; j < 8; j++){
        float a = __shfl(e0v, j, 8);
        float b = __shfl(e1v, j, 8);
        hid += a * Wc1[(2 * j) * 8 + l] + b * Wc1[(2 * j + 1) * 8 + l];
    }
    float contrib = fmaxf(hid, 0.f) * Wc2[l];
    contrib += __shfl_xor(contrib, 1);
    contrib += __shfl_xor(contrib, 2);
    contrib += __shfl_xor(contrib, 4);
    if (lane == 0) out[(size_t)N_NODES * 16 + n] = 1.f / (1.f + __expf(-(contrib + bc2[0])));
}

extern "C" void kernel_launch(void* const* d_in, const int* in_sizes, int n_in,
                              void* d_out, int out_size, void* d_ws, size_t ws_size,
                              hipStream_t stream){
    const float* x    = (const float*)d_in[0];
    const int*   ei   = (const int*)d_in[1];
    const float* W1   = (const float*)d_in[2];
    const float* as1w = (const float*)d_in[3];
    const float* ad1w = (const float*)d_in[4];
    const float* b1   = (const float*)d_in[5];
    const float* W2   = (const float*)d_in[6];
    const float* as2w = (const float*)d_in[7];
    const float* ad2w = (const float*)d_in[8];
    const float* b2   = (const float*)d_in[9];
    const float* Wc1  = (const float*)d_in[10];
    const float* bc1  = (const float*)d_in[11];
    const float* Wc2  = (const float*)d_in[12];
    const float* bc2  = (const float*)d_in[13];
    float* out = (float*)d_out;
    const int* src = ei;
    const int* dst = ei + N_EDGES;

    float* ws   = (float*)d_ws;
    float* hL1  = ws;                                   // N*128 f32
    float* a_s1 = hL1 + (size_t)N_NODES * F1;           // N*4
    float* a_d1 = a_s1 + (size_t)N_NODES * 4;           // N*4
    float* a_s2 = a_d1 + (size_t)N_NODES * 4;           // N
    float* a_d2 = a_s2 + N_NODES;                       // N
    __half* h1h = (__half*)(a_d2 + N_NODES);            // N*128 f16
    __half* h2h = h1h + (size_t)N_NODES * F1;           // N*16 f16
    int* bucketCnt = (int*)(h2h + (size_t)N_NODES * 16);// NB
    int* row_ptr  = bucketCnt + NB;                     // N+1
    int* esrc     = row_ptr + N_NODES + 1;              // E
    unsigned int* ebuf = (unsigned int*)(esrc + N_EDGES); // NB*BCAP

    hipMemsetAsync(bucketCnt, 0, NB * sizeof(int), stream);
    k_bin_fill<<<(N_EDGES + 4095) / 4096, 256, 0, stream>>>(src, dst, bucketCnt, ebuf);
    k_local_csr<<<NB, 1024, 0, stream>>>(bucketCnt, ebuf, row_ptr, esrc);

    k_dense1<<<N_NODES / 8, 256, 0, stream>>>(x, W1, as1w, ad1w, h1h, a_s1, a_d1);
    k_agg1<<<N_NODES / 4, 256, 0, stream>>>(h1h, a_s1, a_d1, row_ptr, esrc, b1, hL1);
    k_dense2<<<N_NODES / 16, 256, 0, stream>>>(hL1, W2, as2w, ad2w, h2h, a_s2, a_d2);
    k_agg2<<<N_NODES / 4, 256, 0, stream>>>(h2h, a_s2, a_d2, row_ptr, esrc, b2, Wc1, bc1, Wc2, bc2, out);
}